// Round 3
// baseline (10318.486 us; speedup 1.0000x reference)
//
#include <hip/hip_runtime.h>
#include <stdint.h>

#define BB 256
#define TT 512
#define HH 512
#define NBLK 192
#define SSTR 16
#define BBHH (BB*HH)

typedef __bf16 bf16x8 __attribute__((ext_vector_type(8)));
typedef float f32x4 __attribute__((ext_vector_type(4)));

static __device__ __forceinline__ unsigned short f2bf(float f) {
    unsigned int u = __builtin_bit_cast(unsigned int, f);
    return (unsigned short)((u + 0x7fffu + ((u >> 16) & 1u)) >> 16);
}
static __device__ __forceinline__ bf16x8 packbf8(const float* p) {
    float4 a = *reinterpret_cast<const float4*>(p);
    float4 b = *reinterpret_cast<const float4*>(p + 4);
    unsigned short us[8] = { f2bf(a.x), f2bf(a.y), f2bf(a.z), f2bf(a.w),
                             f2bf(b.x), f2bf(b.y), f2bf(b.z), f2bf(b.w) };
    uint4 u; __builtin_memcpy(&u, us, 16);
    return __builtin_bit_cast(bf16x8, u);
}
static __device__ __forceinline__ float sigm(float x){ return 1.0f/(1.0f+__expf(-x)); }
static __device__ __forceinline__ float tanh_fast(float x){ return 2.0f/(1.0f+__expf(-2.0f*x)) - 1.0f; }

// system-coherent (LLC) access path: stores write through past L2, loads bypass L1/L2
static __device__ __forceinline__ void ld_sys(uint4& d, const void* p) {
    asm volatile("global_load_dwordx4 %0, %1, off sc0 sc1" : "=v"(d) : "v"(p));
}
static __device__ __forceinline__ void st_sys_u16(void* p, unsigned int v) {
    asm volatile("global_store_short %0, %1, off sc0 sc1" :: "v"(p), "v"(v) : "memory");
}
#define WAITVM(N) asm volatile("s_waitcnt vmcnt(" #N ")" ::: "memory")

// zero the parity-1 h buffers (read as h_{-1}) and the barrier slots
__global__ __launch_bounds__(256) void prep_zero(unsigned short* __restrict__ h1p,
                                                 unsigned short* __restrict__ h2p,
                                                 int* __restrict__ slots) {
    int i = blockIdx.x * blockDim.x + threadIdx.x;
    for (int k = i; k < BBHH; k += gridDim.x * blockDim.x) { h1p[k] = 0; h2p[k] = 0; }
    if (i < NBLK * SSTR) slots[i] = 0;
}

// Persistent pipelined 2-layer LSTM, K-split waves, no spills, no L2 flushes.
// Blocks 0..63  (L0): rows rg*64 (rg=bid>>4), cols cp*32 (cp=bid&15).
//   wave w: pair p=w>>1 -> cols cp*32+p*16; K-half kh=w&1 -> k0=kh*256. Whh0.
//   wave kh finalizes RT {2kh, 2kh+1}, writes the other two RTs' partials to LDS.
// Blocks 64..191 (L1): q=bid-64: rows (q>>5)*64, cols (q&31)*16.
//   wave w: matmul mm=w>>1 (0:Wih1@h1_t, 1:Whh1@h2_{t-1}), K-half kh=w&1.
//   4 waves form one K=1024 reduction quad; wave w finalizes RT w.
// Per wave: 128 weight VGPRs (wb[8][4], packed bf16 once), 128 MFMA/step,
// c-state lane-resident f32. h via sc0sc1 (LLC) loads/stores; release =
// vmcnt(0) + relaxed agent slot store; acquire = spin + syncthreads. No fences.
__global__ __launch_bounds__(256, 1) void lstm_persist(
    const float* __restrict__ x,        // [B][T]
    const float* __restrict__ wih0,     // [2048]
    const float* __restrict__ Whh0,     // [2048][512] f32
    const float* __restrict__ Wih1,     // [2048][512] f32
    const float* __restrict__ Whh1,     // [2048][512] f32
    unsigned short* __restrict__ h1buf, // 2 x [B][H] bf16 (parity by t)
    unsigned short* __restrict__ h2buf, // 2 x [B][H] bf16 (parity by t)
    int* __restrict__ slots)
{
    __shared__ float xch[4][64][64];    // [slot][rt*16+g*4+r][lane]

    const int tid = threadIdx.x;
    const int w   = tid >> 6;
    const int l   = tid & 63;
    const int ln  = l & 15;
    const int kq  = l >> 4;
    const int bid = blockIdx.x;
    const bool isL0 = bid < 64;

    int m0, n0, k0, mm = 0, kh;
    const float* Wsrc;
    if (isL0) {
        const int rg = bid >> 4, cp = bid & 15;
        const int p = w >> 1;
        kh = w & 1;
        m0 = rg * 64;
        n0 = cp * 32 + p * 16;
        k0 = kh * 256;
        Wsrc = Whh0;
    } else {
        const int q = bid - 64;
        mm = w >> 1;
        kh = w & 1;
        m0 = (q >> 5) * 64;
        n0 = (q & 31) * 16;
        k0 = kh * 256;
        Wsrc = mm ? Whh1 : Wih1;
    }

    // ---- one-time weight preload: 16 cols x 4 gates x K=256 slice -> 128 VGPRs ----
    bf16x8 wb[8][4];
    #pragma unroll
    for (int g = 0; g < 4; ++g) {
        const float* wr = Wsrc + (size_t)(g * HH + n0 + ln) * HH + k0 + kq * 8;
        #pragma unroll
        for (int kb = 0; kb < 8; ++kb)
            wb[kb][g] = packbf8(wr + kb * 32);
    }

    float wi0 = 0.f, wf0 = 0.f, wg0 = 0.f, wo0 = 0.f;
    if (isL0) {
        wi0 = wih0[n0 + ln];
        wf0 = wih0[512 + n0 + ln];
        wg0 = wih0[1024 + n0 + ln];
        wo0 = wih0[1536 + n0 + ln];
    }

    float cst[8];
    #pragma unroll
    for (int i = 0; i < 8; ++i) cst[i] = 0.f;

    for (int s = 0; s <= TT; ++s) {
        const bool active = isL0 ? (s < TT) : (s >= 1);
        if (active) {
            const int t = isL0 ? s : s - 1;
            const unsigned short* hp;
            if (isL0)    hp = h1buf + ((t - 1) & 1) * BBHH;  // h1_{t-1}
            else if (mm) hp = h2buf + ((t - 1) & 1) * BBHH;  // h2_{t-1}
            else         hp = h1buf + (t & 1) * BBHH;        // h1_t

            f32x4 acc[4][4];
            #pragma unroll
            for (int rt = 0; rt < 4; ++rt)
                #pragma unroll
                for (int g = 0; g < 4; ++g) acc[rt][g] = (f32x4){0.f,0.f,0.f,0.f};

            const char* abase = (const char*)(hp + (size_t)(m0 + ln) * HH + k0 + kq * 8);
            // rt stride 16*HH*2 = 16384 B, kb stride 32*2 = 64 B
            uint4 A[3][4];
            #pragma unroll
            for (int rt = 0; rt < 4; ++rt) ld_sys(A[0][rt], abase + rt * 16384);
            #pragma unroll
            for (int rt = 0; rt < 4; ++rt) ld_sys(A[1][rt], abase + rt * 16384 + 64);
            #pragma unroll
            for (int kb = 0; kb < 8; ++kb) {
                if (kb < 6) {
                    #pragma unroll
                    for (int rt = 0; rt < 4; ++rt)
                        ld_sys(A[(kb + 2) % 3][rt], abase + rt * 16384 + (kb + 2) * 64);
                    WAITVM(8);
                } else if (kb == 6) {
                    WAITVM(4);
                } else {
                    WAITVM(0);
                }
                __builtin_amdgcn_sched_barrier(0);
                #pragma unroll
                for (int rt = 0; rt < 4; ++rt) {
                    bf16x8 av = __builtin_bit_cast(bf16x8, A[kb % 3][rt]);
                    #pragma unroll
                    for (int g = 0; g < 4; ++g)
                        acc[rt][g] = __builtin_amdgcn_mfma_f32_16x16x32_bf16(av, wb[kb][g], acc[rt][g], 0, 0, 0);
                }
            }

            if (isL0) {
                // write non-finalized RTs {2-2kh, 3-2kh}, finalize {2kh, 2kh+1}
                const int rtW0 = 2 - 2 * kh, rtF0 = 2 * kh;
                #pragma unroll
                for (int j = 0; j < 2; ++j) {
                    const int rt = rtW0 + j;
                    #pragma unroll
                    for (int g = 0; g < 4; ++g)
                        #pragma unroll
                        for (int r = 0; r < 4; ++r)
                            xch[w][rt * 16 + g * 4 + r][l] = acc[rt][g][r];
                }
                __syncthreads();
                unsigned short* ho = h1buf + (t & 1) * BBHH;
                #pragma unroll
                for (int j = 0; j < 2; ++j) {
                    const int rt = rtF0 + j;
                    #pragma unroll
                    for (int r = 0; r < 4; ++r) {
                        float gi = acc[rt][0][r] + xch[w ^ 1][rt * 16 + 0 + r][l];
                        float gf = acc[rt][1][r] + xch[w ^ 1][rt * 16 + 4 + r][l];
                        float gg = acc[rt][2][r] + xch[w ^ 1][rt * 16 + 8 + r][l];
                        float go = acc[rt][3][r] + xch[w ^ 1][rt * 16 + 12 + r][l];
                        const int m = m0 + rt * 16 + kq * 4 + r;
                        const float xv = x[m * TT + t];
                        gi += xv * wi0; gf += xv * wf0; gg += xv * wg0; go += xv * wo0;
                        const float c = sigm(gf) * cst[j * 4 + r] + sigm(gi) * tanh_fast(gg);
                        cst[j * 4 + r] = c;
                        st_sys_u16(ho + m * HH + n0 + ln, (unsigned int)f2bf(sigm(go) * tanh_fast(c)));
                    }
                }
            } else {
                #pragma unroll
                for (int rt = 0; rt < 4; ++rt) {
                    if (rt != w) {
                        #pragma unroll
                        for (int g = 0; g < 4; ++g)
                            #pragma unroll
                            for (int r = 0; r < 4; ++r)
                                xch[w][rt * 16 + g * 4 + r][l] = acc[rt][g][r];
                    }
                }
                __syncthreads();
                unsigned short* ho = h2buf + (t & 1) * BBHH;
                #pragma unroll
                for (int r = 0; r < 4; ++r) {
                    float gi = acc[w][0][r], gf = acc[w][1][r], gg = acc[w][2][r], go = acc[w][3][r];
                    #pragma unroll
                    for (int wp = 0; wp < 4; ++wp) {
                        if (wp != w) {
                            gi += xch[wp][w * 16 + 0 + r][l];
                            gf += xch[wp][w * 16 + 4 + r][l];
                            gg += xch[wp][w * 16 + 8 + r][l];
                            go += xch[wp][w * 16 + 12 + r][l];
                        }
                    }
                    const int m = m0 + w * 16 + kq * 4 + r;
                    const float c = sigm(gf) * cst[r] + sigm(gi) * tanh_fast(gg);
                    cst[r] = c;
                    st_sys_u16(ho + m * HH + n0 + ln, (unsigned int)f2bf(sigm(go) * tanh_fast(c)));
                }
            }
        }

        // ---- grid barrier: release = vmcnt drain + slot store; acquire = spin ----
        if (s < TT) {
            WAITVM(0);               // own sc11 h-stores acked at coherence point
            __syncthreads();         // whole block drained
            if (tid == 0)
                __hip_atomic_store(slots + bid * SSTR, s + 1,
                                   __ATOMIC_RELAXED, __HIP_MEMORY_SCOPE_AGENT);
            if (tid < NBLK) {
                while (__hip_atomic_load(slots + tid * SSTR,
                                         __ATOMIC_RELAXED, __HIP_MEMORY_SCOPE_AGENT) < s + 1) {
                    __builtin_amdgcn_s_sleep(2);
                }
            }
            __builtin_amdgcn_sched_barrier(0);
            __syncthreads();
        }
    }
}

// ---- final: LayerNorm(last h2) @ w_out^T, one 64-lane block per batch row ----
__global__ __launch_bounds__(64) void ln_out_k(const unsigned short* __restrict__ h2,
                                               const float* __restrict__ gamma,
                                               const float* __restrict__ beta,
                                               const float* __restrict__ wout,
                                               float* __restrict__ out)
{
    const int row = blockIdx.x;
    const int lane = threadIdx.x;
    uint4 u = *reinterpret_cast<const uint4*>(h2 + row * HH + lane * 8);
    unsigned short us[8];
    *reinterpret_cast<uint4*>(us) = u;
    float v[8];
    #pragma unroll
    for (int j = 0; j < 8; ++j) {
        unsigned int ww = ((unsigned int)us[j]) << 16;
        v[j] = __builtin_bit_cast(float, ww);
    }
    float sum = 0.f;
    #pragma unroll
    for (int j = 0; j < 8; ++j) sum += v[j];
    #pragma unroll
    for (int o = 32; o >= 1; o >>= 1) sum += __shfl_xor(sum, o);
    const float mu = sum * (1.0f / 512.0f);

    float vs = 0.f;
    #pragma unroll
    for (int j = 0; j < 8; ++j) { float d = v[j] - mu; vs += d * d; }
    #pragma unroll
    for (int o = 32; o >= 1; o >>= 1) vs += __shfl_xor(vs, o);
    const float inv = rsqrtf(vs * (1.0f / 512.0f) + 1e-5f);

    float dot = 0.f;
    #pragma unroll
    for (int j = 0; j < 8; ++j) {
        const int c = lane * 8 + j;
        dot += ((v[j] - mu) * inv * gamma[c] + beta[c]) * wout[c];
    }
    #pragma unroll
    for (int o = 32; o >= 1; o >>= 1) dot += __shfl_xor(dot, o);
    if (lane == 0) out[row] = dot;
}

extern "C" void kernel_launch(void* const* d_in, const int* in_sizes, int n_in,
                              void* d_out, int out_size, void* d_ws, size_t ws_size,
                              hipStream_t stream) {
    const float* x     = (const float*)d_in[0];
    const float* wih0  = (const float*)d_in[1];
    const float* whh0  = (const float*)d_in[2];
    const float* wih1  = (const float*)d_in[3];
    const float* whh1  = (const float*)d_in[4];
    const float* gamma = (const float*)d_in[5];
    const float* beta  = (const float*)d_in[6];
    const float* wout  = (const float*)d_in[7];

    // ws layout: h1buf 2x256KB | h2buf 2x256KB | slots 12KB
    char* ws = (char*)d_ws;
    unsigned short* h1buf = (unsigned short*)(ws);
    unsigned short* h2buf = (unsigned short*)(ws + (512u << 10));
    int* slots            = (int*)(ws + (1024u << 10));

    hipLaunchKernelGGL(prep_zero, dim3(64), dim3(256), 0, stream,
                       h1buf + BBHH, h2buf + BBHH, slots);

    hipLaunchKernelGGL(lstm_persist, dim3(NBLK), dim3(256), 0, stream,
                       x, wih0, whh0, wih1, whh1, h1buf, h2buf, slots);

    // final h2 is parity (T-1)&1 == 1
    hipLaunchKernelGGL(ln_out_k, dim3(BB), dim3(64), 0, stream,
                       h2buf + BBHH, gamma, beta, wout, (float*)d_out);
}

// Round 6
// 7436.288 us; speedup vs baseline: 1.3876x; 1.3876x over previous
//
#include <hip/hip_runtime.h>
#include <stdint.h>

#define BB 256
#define TT 512
#define HH 512
#define NBLK 192
#define SSTR 16
#define BBHH (BB*HH)

typedef __bf16 bf16x8 __attribute__((ext_vector_type(8)));
typedef float f32x4 __attribute__((ext_vector_type(4)));
typedef unsigned int u32x2 __attribute__((ext_vector_type(2)));
typedef unsigned int u32x4 __attribute__((ext_vector_type(4)));

static __device__ __forceinline__ unsigned short f2bf(float f) {
    unsigned int u = __builtin_bit_cast(unsigned int, f);
    return (unsigned short)((u + 0x7fffu + ((u >> 16) & 1u)) >> 16);
}
static __device__ __forceinline__ bf16x8 packbf8(const float* p) {
    float4 a = *reinterpret_cast<const float4*>(p);
    float4 b = *reinterpret_cast<const float4*>(p + 4);
    unsigned short us[8] = { f2bf(a.x), f2bf(a.y), f2bf(a.z), f2bf(a.w),
                             f2bf(b.x), f2bf(b.y), f2bf(b.z), f2bf(b.w) };
    uint4 u; __builtin_memcpy(&u, us, 16);
    return __builtin_bit_cast(bf16x8, u);
}
static __device__ __forceinline__ float sigm(float x){ return 1.0f/(1.0f+__expf(-x)); }
static __device__ __forceinline__ float tanh_fast(float x){ return 2.0f/(1.0f+__expf(-2.0f*x)) - 1.0f; }

// system-coherent (LLC) path: stores write through past L2, loads bypass L1/L2
static __device__ __forceinline__ void ld_sys(uint4& d, const void* p) {
    asm volatile("global_load_dwordx4 %0, %1, off sc0 sc1" : "=v"(d) : "v"(p));
}
static __device__ __forceinline__ void st_sys2(void* p, u32x2 v) {
    asm volatile("global_store_dwordx2 %0, %1, off sc0 sc1" :: "v"(p), "v"(v) : "memory");
}
static __device__ __forceinline__ void st_sys4(void* p, u32x4 v) {
    asm volatile("global_store_dwordx4 %0, %1, off sc0 sc1" :: "v"(p), "v"(v) : "memory");
}
#define WAITVM(N) asm volatile("s_waitcnt vmcnt(" #N ")" ::: "memory")
#define WAITLG    asm volatile("s_waitcnt lgkmcnt(0)" ::: "memory")
#define SBAR      __builtin_amdgcn_sched_barrier(0)

__global__ __launch_bounds__(256) void prep_zero(unsigned short* __restrict__ h1p,
                                                 unsigned short* __restrict__ h2p,
                                                 int* __restrict__ slots) {
    int i = blockIdx.x * blockDim.x + threadIdx.x;
    for (int k = i; k < BBHH; k += gridDim.x * blockDim.x) { h1p[k] = 0; h2p[k] = 0; }
    if (i < NBLK * SSTR) slots[i] = 0;
}

// Persistent pipelined 2-layer LSTM.
// Blocks 0..63 (L0): bh=b>>5 (128-row half), cs=b&31 (16 cols). 8 waves = rh(2) x kh(4):
//   wave rows m0w=bh*128+rh*64 (4 rt), K-slice k0=kh*128 of Whh0. wb[4][4]=64 VGPR.
// Blocks 64..191 (L1): q=b-64: rg=q>>5 (64 rows), cs=q&31. 8 waves = mm(2) x kh(4):
//   mm0: Wih1 x h1_t ; mm1: Whh1 x h2_{t-1}; K-slice kh*128 of that matrix.
// Reduction (per block, 64KB LDS): phase A 8->4 (dump+add), phase B 4->1 per rt owner.
// Epilogue: owner waves update c (regs), transpose h via wave-local LDS tile, store
// coalesced 8-16B/lane sc0sc1 (write-through to LLC).
// Grid sync: 2 independent row-groups of 96 blocks; release = vmcnt(0) + relaxed agent
// slot store; acquire = 96-lane spin. L2 never flushed.
__global__ __launch_bounds__(512, 2) void lstm_persist(
    const float* __restrict__ x,        // [B][T]
    const float* __restrict__ wih0,     // [2048]
    const float* __restrict__ Whh0,     // [2048][512] f32
    const float* __restrict__ Wih1,     // [2048][512] f32
    const float* __restrict__ Whh1,     // [2048][512] f32
    unsigned short* __restrict__ h1buf, // 2 x [B][H] bf16 (parity by t)
    unsigned short* __restrict__ h2buf, // 2 x [B][H] bf16 (parity by t)
    int* __restrict__ slots)
{
    __shared__ float xf[16384];         // 64 KB: 4 slots x 4096 floats

    const int tid = threadIdx.x;
    const int w   = tid >> 6;
    const int l   = tid & 63;
    const int ln  = l & 15;
    const int kq  = l >> 4;
    const int bid = blockIdx.x;
    const bool isL0 = bid < 64;

    int m0w, n0, k0, grp, rh = 0, kh, mm = 0;
    const float* Wsrc;
    if (isL0) {
        const int bh = bid >> 5, cs = bid & 31;
        rh = w >> 2; kh = w & 3;
        grp = bh;
        m0w = bh * 128 + rh * 64;
        n0  = cs * 16;
        k0  = kh * 128;
        Wsrc = Whh0;
    } else {
        const int q = bid - 64;
        const int rg = q >> 5, cs = q & 31;
        mm = w >> 2; kh = w & 3;
        grp = rg >> 1;
        m0w = rg * 64;
        n0  = cs * 16;
        k0  = kh * 128;
        Wsrc = mm ? Whh1 : Wih1;
    }
    const bool dumpA = isL0 ? (kh >= 2) : (mm == 1);
    const int slotOwn = isL0 ? (rh * 2 + (kh & 1)) : (w & 3);

    // ---- one-time weight preload: 16 cols x 4 gates x K=128 -> 64 VGPRs ----
    bf16x8 wb[4][4];
    #pragma unroll
    for (int gg = 0; gg < 4; ++gg) {
        const float* wr = Wsrc + (size_t)(gg * HH + n0 + ln) * HH + k0 + kq * 8;
        #pragma unroll
        for (int kb = 0; kb < 4; ++kb)
            wb[kb][gg] = packbf8(wr + kb * 32);
    }

    float wi0 = 0.f, wf0 = 0.f, wg0 = 0.f, wo0 = 0.f;
    if (isL0) {
        wi0 = wih0[n0 + ln];
        wf0 = wih0[512 + n0 + ln];
        wg0 = wih0[1024 + n0 + ln];
        wo0 = wih0[1536 + n0 + ln];
    }

    float cst[8];
    #pragma unroll
    for (int i = 0; i < 8; ++i) cst[i] = 0.f;

    for (int s = 0; s <= TT; ++s) {
        const bool active = isL0 ? (s < TT) : (s >= 1);
        if (active) {
            const int t = isL0 ? s : s - 1;
            const unsigned short* hp;
            if (isL0)    hp = h1buf + ((t - 1) & 1) * BBHH;  // h1_{t-1}
            else if (mm) hp = h2buf + ((t - 1) & 1) * BBHH;  // h2_{t-1}
            else         hp = h1buf + (t & 1) * BBHH;        // h1_t

            f32x4 acc[4][4];
            #pragma unroll
            for (int rt = 0; rt < 4; ++rt)
                #pragma unroll
                for (int gg = 0; gg < 4; ++gg) acc[rt][gg] = (f32x4){0.f,0.f,0.f,0.f};

            // ---- A loads: 16 x dwordx4 sc0sc1, then counted-wait MFMA ladder ----
            const char* ab = (const char*)(hp + (size_t)(m0w + ln) * HH + k0 + kq * 8);
            uint4 A[4][4];
            #pragma unroll
            for (int kb = 0; kb < 4; ++kb)
                #pragma unroll
                for (int rt = 0; rt < 4; ++rt)
                    ld_sys(A[kb][rt], ab + rt * 16384 + kb * 64);

            #define MFMA_KB(kb) do { \
                _Pragma("unroll") \
                for (int rt = 0; rt < 4; ++rt) { \
                    bf16x8 av = __builtin_bit_cast(bf16x8, A[kb][rt]); \
                    _Pragma("unroll") \
                    for (int gg = 0; gg < 4; ++gg) \
                        acc[rt][gg] = __builtin_amdgcn_mfma_f32_16x16x32_bf16(av, wb[kb][gg], acc[rt][gg], 0, 0, 0); \
                } } while (0)

            WAITVM(12); SBAR; MFMA_KB(0);
            WAITVM(8);  SBAR; MFMA_KB(1);
            WAITVM(4);  SBAR; MFMA_KB(2);
            WAITVM(0);  SBAR; MFMA_KB(3);
            #undef MFMA_KB

            // ---- phase A: 8 -> 4 ----
            if (dumpA) {
                float* sb = xf + slotOwn * 4096;
                #pragma unroll
                for (int rt = 0; rt < 4; ++rt)
                    #pragma unroll
                    for (int gg = 0; gg < 4; ++gg)
                        *(f32x4*)(sb + (rt * 4 + gg) * 256 + l * 4) = acc[rt][gg];
            }
            __syncthreads();
            if (!dumpA) {
                float* sb = xf + slotOwn * 4096;
                #pragma unroll
                for (int rt = 0; rt < 4; ++rt)
                    #pragma unroll
                    for (int gg = 0; gg < 4; ++gg)
                        acc[rt][gg] += *(f32x4*)(sb + (rt * 4 + gg) * 256 + l * 4);
                // ---- phase B write: non-owned rts into OWN slot region ----
                if (isL0) {
                    #pragma unroll
                    for (int j = 0; j < 2; ++j) {
                        const int rt = ((kh ^ 1) * 2 + j);  // partner's rts
                        #pragma unroll
                        for (int gg = 0; gg < 4; ++gg)
                            *(f32x4*)(xf + slotOwn * 4096 + (j * 4 + gg) * 256 + l * 4) = acc[rt][gg];
                    }
                } else {
                    #pragma unroll
                    for (int rt = 0; rt < 4; ++rt) {
                        if (rt != w) {
                            const int jj = rt - (rt > w ? 1 : 0);
                            #pragma unroll
                            for (int gg = 0; gg < 4; ++gg)
                                *(f32x4*)(xf + slotOwn * 4096 + (jj * 4 + gg) * 256 + l * 4) = acc[rt][gg];
                        }
                    }
                }
            }
            __syncthreads();

            // ---- phase B read: gather owned rt(s); static-indexed `own` regs ----
            f32x4 own[2][4];
            if (!dumpA) {
                if (isL0) {
                    #pragma unroll
                    for (int rt = 0; rt < 4; ++rt)
                        if ((rt >> 1) == kh) {
                            #pragma unroll
                            for (int gg = 0; gg < 4; ++gg) own[rt & 1][gg] = acc[rt][gg];
                        }
                    const int partner = rh * 2 + (kh ^ 1);
                    #pragma unroll
                    for (int j = 0; j < 2; ++j)
                        #pragma unroll
                        for (int gg = 0; gg < 4; ++gg)
                            own[j][gg] += *(f32x4*)(xf + partner * 4096 + (j * 4 + gg) * 256 + l * 4);
                } else {
                    #pragma unroll
                    for (int rt = 0; rt < 4; ++rt)
                        if (rt == w) {
                            #pragma unroll
                            for (int gg = 0; gg < 4; ++gg) own[0][gg] = acc[rt][gg];
                        }
                    #pragma unroll
                    for (int s2 = 0; s2 < 4; ++s2) {
                        if (s2 != w) {
                            const int pos = w - (w > s2 ? 1 : 0);
                            #pragma unroll
                            for (int gg = 0; gg < 4; ++gg)
                                own[0][gg] += *(f32x4*)(xf + s2 * 4096 + (pos * 4 + gg) * 256 + l * 4);
                        }
                    }
                }
            }
            __syncthreads();

            // ---- epilogue: cell update + LDS transpose + coalesced store ----
            if (!dumpA) {
                char* trb = (char*)xf + w * 2048;
                if (isL0) {
                    unsigned short* ho = h1buf + (t & 1) * BBHH;
                    #pragma unroll
                    for (int j = 0; j < 2; ++j)
                        #pragma unroll
                        for (int r = 0; r < 4; ++r) {
                            const int row = m0w + (kh * 2 + j) * 16 + kq * 4 + r;
                            const float xv = x[row * TT + t];
                            const float gi = own[j][0][r] + xv * wi0;
                            const float gf = own[j][1][r] + xv * wf0;
                            const float gg2 = own[j][2][r] + xv * wg0;
                            const float go = own[j][3][r] + xv * wo0;
                            const float c = sigm(gf) * cst[j * 4 + r] + sigm(gi) * tanh_fast(gg2);
                            cst[j * 4 + r] = c;
                            *(unsigned short*)(trb + (((j * 16 + kq * 4 + r) * 16) + ln) * 2) =
                                f2bf(sigm(go) * tanh_fast(c));
                        }
                    WAITLG;
                    __builtin_amdgcn_wave_barrier();
                    u32x4 v = *(const u32x4*)(trb + (l >> 1) * 32 + (l & 1) * 16);
                    st_sys4(ho + (size_t)(m0w + kh * 32 + (l >> 1)) * HH + n0 + (l & 1) * 8, v);
                } else {
                    unsigned short* ho = h2buf + (t & 1) * BBHH;
                    #pragma unroll
                    for (int r = 0; r < 4; ++r) {
                        const float gi = own[0][0][r];
                        const float gf = own[0][1][r];
                        const float gg2 = own[0][2][r];
                        const float go = own[0][3][r];
                        const float c = sigm(gf) * cst[r] + sigm(gi) * tanh_fast(gg2);
                        cst[r] = c;
                        *(unsigned short*)(trb + (((kq * 4 + r) * 16) + ln) * 2) =
                            f2bf(sigm(go) * tanh_fast(c));
                    }
                    WAITLG;
                    __builtin_amdgcn_wave_barrier();
                    u32x2 v = *(const u32x2*)(trb + (l >> 2) * 32 + (l & 3) * 8);
                    st_sys2(ho + (size_t)(m0w + w * 16 + (l >> 2)) * HH + n0 + (l & 3) * 4, v);
                }
            }
        }

        // ---- group-local grid barrier (2 groups of 96 blocks) ----
        if (s < TT) {
            WAITVM(0);
            __syncthreads();
            if (tid == 0)
                __hip_atomic_store(slots + bid * SSTR, s + 1,
                                   __ATOMIC_RELAXED, __HIP_MEMORY_SCOPE_AGENT);
            if (tid < 96) {
                const int sid = (tid < 32) ? (grp * 32 + tid) : (64 + grp * 64 + (tid - 32));
                while (__hip_atomic_load(slots + sid * SSTR,
                                         __ATOMIC_RELAXED, __HIP_MEMORY_SCOPE_AGENT) < s + 1) {
                    __builtin_amdgcn_s_sleep(2);
                }
            }
            SBAR;
            __syncthreads();
        }
    }
}

// ---- final: LayerNorm(last h2) @ w_out^T, one 64-lane block per batch row ----
__global__ __launch_bounds__(64) void ln_out_k(const unsigned short* __restrict__ h2,
                                               const float* __restrict__ gamma,
                                               const float* __restrict__ beta,
                                               const float* __restrict__ wout,
                                               float* __restrict__ out)
{
    const int row = blockIdx.x;
    const int lane = threadIdx.x;
    uint4 u = *reinterpret_cast<const uint4*>(h2 + row * HH + lane * 8);
    unsigned short us[8];
    *reinterpret_cast<uint4*>(us) = u;
    float v[8];
    #pragma unroll
    for (int j = 0; j < 8; ++j) {
        unsigned int ww = ((unsigned int)us[j]) << 16;
        v[j] = __builtin_bit_cast(float, ww);
    }
    float sum = 0.f;
    #pragma unroll
    for (int j = 0; j < 8; ++j) sum += v[j];
    #pragma unroll
    for (int o = 32; o >= 1; o >>= 1) sum += __shfl_xor(sum, o);
    const float mu = sum * (1.0f / 512.0f);

    float vs = 0.f;
    #pragma unroll
    for (int j = 0; j < 8; ++j) { float d = v[j] - mu; vs += d * d; }
    #pragma unroll
    for (int o = 32; o >= 1; o >>= 1) vs += __shfl_xor(vs, o);
    const float inv = rsqrtf(vs * (1.0f / 512.0f) + 1e-5f);

    float dot = 0.f;
    #pragma unroll
    for (int j = 0; j < 8; ++j) {
        const int c = lane * 8 + j;
        dot += ((v[j] - mu) * inv * gamma[c] + beta[c]) * wout[c];
    }
    #pragma unroll
    for (int o = 32; o >= 1; o >>= 1) dot += __shfl_xor(dot, o);
    if (lane == 0) out[row] = dot;
}

extern "C" void kernel_launch(void* const* d_in, const int* in_sizes, int n_in,
                              void* d_out, int out_size, void* d_ws, size_t ws_size,
                              hipStream_t stream) {
    const float* x     = (const float*)d_in[0];
    const float* wih0  = (const float*)d_in[1];
    const float* whh0  = (const float*)d_in[2];
    const float* wih1  = (const float*)d_in[3];
    const float* whh1  = (const float*)d_in[4];
    const float* gamma = (const float*)d_in[5];
    const float* beta  = (const float*)d_in[6];
    const float* wout  = (const float*)d_in[7];

    char* ws = (char*)d_ws;
    unsigned short* h1buf = (unsigned short*)(ws);
    unsigned short* h2buf = (unsigned short*)(ws + (512u << 10));
    int* slots            = (int*)(ws + (1024u << 10));

    hipLaunchKernelGGL(prep_zero, dim3(64), dim3(256), 0, stream,
                       h1buf + BBHH, h2buf + BBHH, slots);

    hipLaunchKernelGGL(lstm_persist, dim3(NBLK), dim3(512), 0, stream,
                       x, wih0, whh0, wih1, whh1, h1buf, h2buf, slots);

    hipLaunchKernelGGL(ln_out_k, dim3(BB), dim3(64), 0, stream,
                       h2buf + BBHH, gamma, beta, wout, (float*)d_out);
}

// Round 7
// 2676.720 us; speedup vs baseline: 3.8549x; 2.7781x over previous
//
#include <hip/hip_runtime.h>
#include <stdint.h>

#define BB 256
#define TT 512
#define HH 512
#define NBLK 256
#define SSTR 16
#define BBHH (BB*HH)

typedef __bf16 bf16x8 __attribute__((ext_vector_type(8)));
typedef float f32x4 __attribute__((ext_vector_type(4)));
typedef unsigned int u32x2 __attribute__((ext_vector_type(2)));

static __device__ __forceinline__ unsigned short f2bf(float f) {
    unsigned int u = __builtin_bit_cast(unsigned int, f);
    return (unsigned short)((u + 0x7fffu + ((u >> 16) & 1u)) >> 16);
}
static __device__ __forceinline__ bf16x8 packbf8(const float* p) {
    float4 a = *reinterpret_cast<const float4*>(p);
    float4 b = *reinterpret_cast<const float4*>(p + 4);
    unsigned short us[8] = { f2bf(a.x), f2bf(a.y), f2bf(a.z), f2bf(a.w),
                             f2bf(b.x), f2bf(b.y), f2bf(b.z), f2bf(b.w) };
    uint4 u; __builtin_memcpy(&u, us, 16);
    return __builtin_bit_cast(bf16x8, u);
}
static __device__ __forceinline__ float sigm(float x){ return 1.0f/(1.0f+__expf(-x)); }
static __device__ __forceinline__ float tanh_fast(float x){ return 2.0f/(1.0f+__expf(-2.0f*x)) - 1.0f; }

// system-coherent (LLC) path: stores write through past L2, loads bypass L1/L2
static __device__ __forceinline__ void ld_sys(uint4& d, const void* p) {
    asm volatile("global_load_dwordx4 %0, %1, off sc0 sc1" : "=v"(d) : "v"(p));
}
static __device__ __forceinline__ void st_sys2(void* p, u32x2 v) {
    asm volatile("global_store_dwordx2 %0, %1, off sc0 sc1" :: "v"(p), "v"(v) : "memory");
}
#define WAITVM(N) asm volatile("s_waitcnt vmcnt(" #N ")" ::: "memory")
#define SBAR      __builtin_amdgcn_sched_barrier(0)

__global__ __launch_bounds__(256) void prep_zero(unsigned short* __restrict__ h1p,
                                                 unsigned short* __restrict__ h2p,
                                                 int* __restrict__ slots) {
    int i = blockIdx.x * blockDim.x + threadIdx.x;
    for (int k = i; k < BBHH; k += gridDim.x * blockDim.x) { h1p[k] = 0; h2p[k] = 0; }
    if (i < NBLK * SSTR) slots[i] = 0;
}

// Persistent pipelined 2-layer LSTM. 256 blocks x 256 thr = 1 block/CU, 1 wave/SIMD
// (launch_bounds(256,1) -> up to ~450 unified regs/wave, no spills by construction).
// 8 independent 32-row groups; per group 16 L0 blocks (bid=g*16+cs) + 16 L1 blocks
// (bid=128+g*16+cs); block tile = 32 rows x 32 hcols (cols cs*32).
// L0 wave w = K-quarter kh=w (K=128) of Whh0; wb[2nt][4kb][4gg] = 128 regs.
// L1 wave w = (mm=w>>1, kh=w&1): K-half (256) of (mm? Whh1 : Wih1); wb[2][8][4]=256 regs.
// Each wave: acc[2rt][2nt][4gg], A-loads via sc0sc1 counted-vmcnt ladder.
// Reduce: all 4 waves dump acc to LDS [slot][rt][nt][row16][col16][gg] (XOR-swizzled),
// sync, each wave finalizes 8 rows x 32 cols (4 cells/lane, c-state in cst[4]),
// stores h coalesced 8B/lane via sc0sc1 write-through.
// Grid sync: per-group 32-slot monotone counters; release = vmcnt(0)+syncthreads+
// relaxed agent store; acquire = 32-lane spin. L2 never flushed.
__global__ __launch_bounds__(256, 1) void lstm_persist(
    const float* __restrict__ x,        // [B][T]
    const float* __restrict__ wih0,     // [2048]
    const float* __restrict__ Whh0,     // [2048][512] f32
    const float* __restrict__ Wih1,     // [2048][512] f32
    const float* __restrict__ Whh1,     // [2048][512] f32
    unsigned short* __restrict__ h1buf, // 2 x [B][H] bf16 (parity by t)
    unsigned short* __restrict__ h2buf, // 2 x [B][H] bf16 (parity by t)
    int* __restrict__ slots)
{
    __shared__ float xf[16384];         // 64 KB: [4 slot][2 rt][2 nt][16 row][16 col][4 gg]

    const int tid = threadIdx.x;
    const int w   = tid >> 6;
    const int l   = tid & 63;
    const int ln  = l & 15;
    const int kq  = l >> 4;
    const int bid = blockIdx.x;
    const bool isL0 = bid < 128;

    int g, cs, k0, mm = 0;
    const float* Wsrc;
    if (isL0) {
        g = bid >> 4; cs = bid & 15;
        k0 = w * 128;
        Wsrc = Whh0;
    } else {
        const int q = bid - 128;
        g = q >> 4; cs = q & 15;
        mm = w >> 1;
        k0 = (w & 1) * 256;
        Wsrc = mm ? Whh1 : Wih1;
    }

    // ---- one-time weight preload (L0: 128 regs, L1: 256 regs) ----
    bf16x8 wb[2][8][4];
    if (isL0) {
        #pragma unroll
        for (int nt = 0; nt < 2; ++nt)
            #pragma unroll
            for (int kb = 0; kb < 4; ++kb)
                #pragma unroll
                for (int g4 = 0; g4 < 4; ++g4)
                    wb[nt][kb][g4] = packbf8(Wsrc + (size_t)(g4 * HH + cs * 32 + nt * 16 + ln) * HH + k0 + kb * 32 + kq * 8);
    } else {
        #pragma unroll
        for (int nt = 0; nt < 2; ++nt)
            #pragma unroll
            for (int kb = 0; kb < 8; ++kb)
                #pragma unroll
                for (int g4 = 0; g4 < 4; ++g4)
                    wb[nt][kb][g4] = packbf8(Wsrc + (size_t)(g4 * HH + cs * 32 + nt * 16 + ln) * HH + k0 + kb * 32 + kq * 8);
    }

    // epilogue constants: lane owns row erow, cols cs*32 + (l&7)*4 + 0..3
    const int erow = g * 32 + w * 8 + (l >> 3);
    f32x4 wiv[4] = {};
    if (isL0) {
        #pragma unroll
        for (int j = 0; j < 4; ++j) {
            const int cg = cs * 32 + (l & 7) * 4 + j;
            wiv[j] = (f32x4){ wih0[cg], wih0[512 + cg], wih0[1024 + cg], wih0[1536 + cg] };
        }
    }
    const int rt_r = w >> 1;
    const int rowl = (w & 1) * 8 + (l >> 3);
    const int nt_r = (l >> 2) & 1;
    const int colb = (l & 3) * 4;

    float cst[4] = {0.f, 0.f, 0.f, 0.f};

    for (int s = 0; s <= TT; ++s) {
        const bool active = isL0 ? (s < TT) : (s >= 1);
        if (active) {
            const int t = isL0 ? s : s - 1;
            const unsigned short* hp;
            if (isL0)    hp = h1buf + ((t - 1) & 1) * BBHH;  // h1_{t-1}
            else if (mm) hp = h2buf + ((t - 1) & 1) * BBHH;  // h2_{t-1}
            else         hp = h1buf + (t & 1) * BBHH;        // h1_t

            float xv = 0.f;
            if (isL0) xv = x[(size_t)erow * TT + t];

            f32x4 acc[2][2][4];
            #pragma unroll
            for (int rt = 0; rt < 2; ++rt)
                #pragma unroll
                for (int nt = 0; nt < 2; ++nt)
                    #pragma unroll
                    for (int g4 = 0; g4 < 4; ++g4) acc[rt][nt][g4] = (f32x4){0.f,0.f,0.f,0.f};

            const char* ab = (const char*)(hp + (size_t)(g * 32 + ln) * HH + k0 + kq * 8);
            uint4 A[4][2];
            #pragma unroll
            for (int kb = 0; kb < 4; ++kb) {
                ld_sys(A[kb][0], ab + kb * 64);
                ld_sys(A[kb][1], ab + 16384 + kb * 64);
            }

            #define MK(kb, ap) do { \
                _Pragma("unroll") \
                for (int rt = 0; rt < 2; ++rt) { \
                    bf16x8 av = __builtin_bit_cast(bf16x8, A[ap][rt]); \
                    _Pragma("unroll") \
                    for (int nt = 0; nt < 2; ++nt) \
                        _Pragma("unroll") \
                        for (int g4 = 0; g4 < 4; ++g4) \
                            acc[rt][nt][g4] = __builtin_amdgcn_mfma_f32_16x16x32_bf16(av, wb[nt][kb][g4], acc[rt][nt][g4], 0, 0, 0); \
                } } while (0)

            if (isL0) {
                WAITVM(6); SBAR; MK(0, 0);
                WAITVM(4); SBAR; MK(1, 1);
                WAITVM(2); SBAR; MK(2, 2);
                WAITVM(0); SBAR; MK(3, 3);
            } else {
                WAITVM(6); SBAR; MK(0, 0);
                ld_sys(A[0][0], ab + 256); ld_sys(A[0][1], ab + 16384 + 256);
                WAITVM(6); SBAR; MK(1, 1);
                ld_sys(A[1][0], ab + 320); ld_sys(A[1][1], ab + 16384 + 320);
                WAITVM(6); SBAR; MK(2, 2);
                ld_sys(A[2][0], ab + 384); ld_sys(A[2][1], ab + 16384 + 384);
                WAITVM(6); SBAR; MK(3, 3);
                ld_sys(A[3][0], ab + 448); ld_sys(A[3][1], ab + 16384 + 448);
                WAITVM(6); SBAR; MK(4, 0);
                WAITVM(4); SBAR; MK(5, 1);
                WAITVM(2); SBAR; MK(6, 2);
                WAITVM(0); SBAR; MK(7, 3);
            }
            #undef MK

            // ---- dump all acc to LDS (XOR-swizzled [slot][rt][nt][row][col][gg]) ----
            #pragma unroll
            for (int rt = 0; rt < 2; ++rt)
                #pragma unroll
                for (int nt = 0; nt < 2; ++nt)
                    #pragma unroll
                    for (int r = 0; r < 4; ++r) {
                        const int row16 = kq * 4 + r;
                        f32x4 v = { acc[rt][nt][0][r], acc[rt][nt][1][r],
                                    acc[rt][nt][2][r], acc[rt][nt][3][r] };
                        *(f32x4*)((char*)xf + (((w * 2 + rt) * 2 + nt) * 16 + row16) * 256
                                            + ((ln * 16) ^ ((row16 & 7) << 4))) = v;
                    }
            __syncthreads();

            // ---- gather 4 slots, cell update, coalesced h store ----
            unsigned short* ho = (isL0 ? h1buf : h2buf) + (t & 1) * BBHH;
            unsigned short hout[4];
            #pragma unroll
            for (int j = 0; j < 4; ++j) {
                f32x4 sv = (f32x4){0.f, 0.f, 0.f, 0.f};
                #pragma unroll
                for (int s4 = 0; s4 < 4; ++s4)
                    sv += *(const f32x4*)((const char*)xf + (((s4 * 2 + rt_r) * 2 + nt_r) * 16 + rowl) * 256
                                                          + (((colb + j) * 16) ^ ((rowl & 7) << 4)));
                if (isL0) sv += wiv[j] * xv;
                const float c = sigm(sv.y) * cst[j] + sigm(sv.x) * tanh_fast(sv.z);
                cst[j] = c;
                hout[j] = f2bf(sigm(sv.w) * tanh_fast(c));
            }
            u32x2 hv;
            hv.x = (unsigned int)hout[0] | ((unsigned int)hout[1] << 16);
            hv.y = (unsigned int)hout[2] | ((unsigned int)hout[3] << 16);
            st_sys2(ho + (size_t)erow * HH + cs * 32 + (l & 7) * 4, hv);
        }

        // ---- group-local grid barrier (32 blocks: 16 L0 + 16 L1) ----
        if (s < TT) {
            WAITVM(0);
            __syncthreads();
            if (tid == 0)
                __hip_atomic_store(slots + bid * SSTR, s + 1,
                                   __ATOMIC_RELAXED, __HIP_MEMORY_SCOPE_AGENT);
            if (tid < 32) {
                const int sid = (tid < 16) ? (g * 16 + tid) : (128 + g * 16 + (tid - 16));
                while (__hip_atomic_load(slots + sid * SSTR,
                                         __ATOMIC_RELAXED, __HIP_MEMORY_SCOPE_AGENT) < s + 1) {
                    __builtin_amdgcn_s_sleep(2);
                }
            }
            SBAR;
            __syncthreads();
        }
    }
}

// ---- final: LayerNorm(last h2) @ w_out^T, one 64-lane block per batch row ----
__global__ __launch_bounds__(64) void ln_out_k(const unsigned short* __restrict__ h2,
                                               const float* __restrict__ gamma,
                                               const float* __restrict__ beta,
                                               const float* __restrict__ wout,
                                               float* __restrict__ out)
{
    const int row = blockIdx.x;
    const int lane = threadIdx.x;
    uint4 u = *reinterpret_cast<const uint4*>(h2 + row * HH + lane * 8);
    unsigned short us[8];
    *reinterpret_cast<uint4*>(us) = u;
    float v[8];
    #pragma unroll
    for (int j = 0; j < 8; ++j) {
        unsigned int ww = ((unsigned int)us[j]) << 16;
        v[j] = __builtin_bit_cast(float, ww);
    }
    float sum = 0.f;
    #pragma unroll
    for (int j = 0; j < 8; ++j) sum += v[j];
    #pragma unroll
    for (int o = 32; o >= 1; o >>= 1) sum += __shfl_xor(sum, o);
    const float mu = sum * (1.0f / 512.0f);

    float vs = 0.f;
    #pragma unroll
    for (int j = 0; j < 8; ++j) { float d = v[j] - mu; vs += d * d; }
    #pragma unroll
    for (int o = 32; o >= 1; o >>= 1) vs += __shfl_xor(vs, o);
    const float inv = rsqrtf(vs * (1.0f / 512.0f) + 1e-5f);

    float dot = 0.f;
    #pragma unroll
    for (int j = 0; j < 8; ++j) {
        const int c = lane * 8 + j;
        dot += ((v[j] - mu) * inv * gamma[c] + beta[c]) * wout[c];
    }
    #pragma unroll
    for (int o = 32; o >= 1; o >>= 1) dot += __shfl_xor(dot, o);
    if (lane == 0) out[row] = dot;
}

extern "C" void kernel_launch(void* const* d_in, const int* in_sizes, int n_in,
                              void* d_out, int out_size, void* d_ws, size_t ws_size,
                              hipStream_t stream) {
    const float* x     = (const float*)d_in[0];
    const float* wih0  = (const float*)d_in[1];
    const float* whh0  = (const float*)d_in[2];
    const float* wih1  = (const float*)d_in[3];
    const float* whh1  = (const float*)d_in[4];
    const float* gamma = (const float*)d_in[5];
    const float* beta  = (const float*)d_in[6];
    const float* wout  = (const float*)d_in[7];

    char* ws = (char*)d_ws;
    unsigned short* h1buf = (unsigned short*)(ws);
    unsigned short* h2buf = (unsigned short*)(ws + (512u << 10));
    int* slots            = (int*)(ws + (1024u << 10));

    hipLaunchKernelGGL(prep_zero, dim3(64), dim3(256), 0, stream,
                       h1buf + BBHH, h2buf + BBHH, slots);

    hipLaunchKernelGGL(lstm_persist, dim3(NBLK), dim3(256), 0, stream,
                       x, wih0, whh0, wih1, whh1, h1buf, h2buf, slots);

    hipLaunchKernelGGL(ln_out_k, dim3(BB), dim3(64), 0, stream,
                       h2buf + BBHH, gamma, beta, wout, (float*)d_out);
}